// Round 6
// baseline (169.236 us; speedup 1.0000x reference)
//
#include <hip/hip_runtime.h>

typedef __attribute__((ext_vector_type(8))) short short8;
typedef __attribute__((ext_vector_type(4))) float floatx4;
typedef __attribute__((ext_vector_type(4))) float float4v;
typedef __attribute__((ext_vector_type(4))) unsigned short ushort4v;

#define TILE_M 64
#define TILE_SHORTS (TILE_M * 256)   // 16384 shorts = 32 KB per buffer (flat, swizzled)

static __device__ __forceinline__ unsigned short f2bf(float x) {
    unsigned int u = __builtin_bit_cast(unsigned int, x);
    unsigned int r = (u + 0x7FFFu + ((u >> 16) & 1u)) >> 16;
    return (unsigned short)r;
}

// async 16B global -> LDS (DMA, lands at lds_base + lane*16)
static __device__ __forceinline__ void gld16(const unsigned short* g, unsigned short* l) {
    __builtin_amdgcn_global_load_lds(
        (const __attribute__((address_space(1))) unsigned int*)g,
        (__attribute__((address_space(3))) unsigned int*)l, 16, 0, 0);
}

// Prep: tables fp32 -> bf16 only (W1 is now converted inside edge_mlp).
__global__ void prep_tables(const float* __restrict__ zd, const float* __restrict__ zs,
                            int nd4, int ns4,
                            unsigned short* __restrict__ outd, unsigned short* __restrict__ outs) {
    int i = blockIdx.x * 256 + threadIdx.x;
    int total4 = nd4 + ns4;
    if (i >= total4) return;
    const float* src; unsigned short* dst; int j;
    if (i < nd4) { src = zd; dst = outd; j = i; }
    else         { src = zs; dst = outs; j = i - nd4; }
    float4v v = *reinterpret_cast<const float4v*>(src + (size_t)j * 4);
    ushort4v o;
    o.x = f2bf(v.x); o.y = f2bf(v.y); o.z = f2bf(v.z); o.w = f2bf(v.w);
    *reinterpret_cast<ushort4v*>(dst + (size_t)j * 4) = o;
}

// LDS tile layout (flat, DMA-compatible, XOR-swizzled):
// chunk slot c (16B) holds edge e = c>>5, physical chunk jx = c&31, storing
// logical k-chunk j = jx ^ (e&7) of edge e's 256-short concat row.
//
// Software pipeline per round r (single barrier per round):
//   barrier -> issue DMA(t_{r+1}) -> E2(t_{r-2}): red->out -> E1(t_{r-1}): acc->red -> K(t_r)
// E1/E2 interleave with K across waves (wave drift) — no work trapped before the barrier.
__global__ __launch_bounds__(256, 2) void edge_mlp(
    const unsigned short* __restrict__ zd, const unsigned short* __restrict__ zs,
    const int* __restrict__ row, const int* __restrict__ col,
    const float* __restrict__ W1,
    const float* __restrict__ b1, const float* __restrict__ w2,
    const float* __restrict__ b2, float* __restrict__ out, int ntiles)
{
    __shared__ unsigned short lds_a[2][TILE_SHORTS];  // 64 KB double buffer
    __shared__ float red[2][2][TILE_M];               // 1 KB, slot = tile_index & 1

    const int tid  = threadIdx.x;
    const int lane = tid & 63;
    const int wave = tid >> 6;
    const int wh   = wave >> 1;          // hidden half: [wh*64, wh*64+64)
    const int we   = wave & 1;           // edge half:   [we*32, we*32+32)
    const int l15  = lane & 15;
    const int quad = lane >> 4;
    const int whbase = wh * 64;

    // ---- persistent W1 A-fragments, converted directly from fp32 W1 (128 VGPRs) ----
    // A[m=hidden][k]: m = whbase + mt*16 + l15, k = s*32 + quad*8 + j
    short8 wfrag[32];                    // [s*4 + mt]
    #pragma unroll
    for (int s = 0; s < 8; ++s) {
        #pragma unroll
        for (int mt = 0; mt < 4; ++mt) {
            const float* p = W1 + (size_t)(s * 32 + quad * 8) * 128 + whbase + mt * 16 + l15;
            short8 f;
            #pragma unroll
            for (int j = 0; j < 8; ++j)
                f[j] = (short)f2bf(p[(size_t)j * 128]);
            wfrag[s * 4 + mt] = f;
        }
    }

    // ---- persistent epilogue constants ----
    float4v b1v[4], w2v[4];
    #pragma unroll
    for (int mt = 0; mt < 4; ++mt) {
        b1v[mt] = *reinterpret_cast<const float4v*>(&b1[whbase + mt * 16 + quad * 4]);
        w2v[mt] = *reinterpret_cast<const float4v*>(&w2[whbase + mt * 16 + quad * 4]);
    }
    const float b2v = b2[0];

    // ---- fixed staging geometry for this thread ----
    const int e0 = tid >> 5;             // edges e0 + 8i
    const int jxw = tid & 31;            // physical chunk this thread fills
    const int jlog = jxw ^ (e0 & 7);     // logical k-chunk it fetches
    const unsigned short* tab = (jlog >= 16) ? zs : zd;
    const int* idxp = (jlog >= 16) ? col : row;
    const int koff = (jlog & 15) * 8;

    // reader swizzle constants
    const int hb = (l15 >> 2) & 1;
    const int qx = quad ^ (l15 & 3);

    const int G = gridDim.x;
    const int R = ntiles / G;            // uniform across blocks (16384/512 = 32)
    const long t0 = blockIdx.x;

    // ---- prologue: DMA tile t0 into buf 0; prefetch indices for t0+G ----
    int nidx[8];
    #pragma unroll
    for (int i = 0; i < 8; ++i) nidx[i] = idxp[t0 * TILE_M + e0 + 8 * i];
    #pragma unroll
    for (int i = 0; i < 8; ++i)
        gld16(tab + (size_t)nidx[i] * 128 + koff, &lds_a[0][2048 * i + 512 * wave]);
    {
        long t1 = t0 + G; if (R < 2) t1 = t0;
        #pragma unroll
        for (int i = 0; i < 8; ++i) nidx[i] = idxp[t1 * TILE_M + e0 + 8 * i];
    }

    floatx4 acc[2][4];                   // [et][mt]

    for (int r = 0; r < R; ++r) {
        const long t = t0 + (long)r * G;

        // single barrier: drains DMA(t) into buf[r&1], syncs red writes of round r-1
        __syncthreads();

        // (a) issue async DMA for tile t+G into the other buffer
        if (r + 1 < R) {
            #pragma unroll
            for (int i = 0; i < 8; ++i)
                gld16(tab + (size_t)nidx[i] * 128 + koff,
                      &lds_a[(r + 1) & 1][2048 * i + 512 * wave]);
        }
        // (b) prefetch indices for tile t+2G
        {
            long t2 = t0 + (long)(r + 2) * G; if (r + 2 >= R) t2 = t0;
            #pragma unroll
            for (int i = 0; i < 8; ++i) nidx[i] = idxp[t2 * TILE_M + e0 + 8 * i];
        }

        // (c) E2: write out for tile t-2G (red slot r&1), spread over all 4 waves
        if (r >= 2 && lane < 16) {
            int eo = wave * 16 + l15;
            out[(t - 2 * G) * TILE_M + eo] =
                red[r & 1][0][eo] + red[r & 1][1][eo] + b2v;
        }

        // (d) E1: reduce acc of tile t-G into red slot (r-1)&1
        if (r >= 1) {
            const int slot = (r - 1) & 1;
            #pragma unroll
            for (int et = 0; et < 2; ++et) {
                float v = 0.f;
                #pragma unroll
                for (int mt = 0; mt < 4; ++mt)
                    #pragma unroll
                    for (int rr = 0; rr < 4; ++rr) {
                        float h = acc[et][mt][rr] + b1v[mt][rr];
                        h = h > 0.f ? h : 0.f;
                        v += h * w2v[mt][rr];
                    }
                v += __shfl_xor(v, 16);
                v += __shfl_xor(v, 32);
                if (lane < 16) red[slot][wh][we * 32 + et * 16 + l15] = v;
            }
        }

        // (e) K-loop: acc = W1half^T x Zhalf on buf[r&1]
        const unsigned short* buf = lds_a[r & 1];
        #pragma unroll
        for (int et = 0; et < 2; ++et)
            #pragma unroll
            for (int mt = 0; mt < 4; ++mt)
                acc[et][mt] = (floatx4)(0.0f);

        #pragma unroll
        for (int s = 0; s < 8; ++s) {
            const int sx = s ^ hb;
            short8 ef[2];
            #pragma unroll
            for (int et = 0; et < 2; ++et) {
                int e = we * 32 + et * 16 + l15;
                ef[et] = *reinterpret_cast<const short8*>(&buf[e * 256 + sx * 32 + qx * 8]);
            }
            #pragma unroll
            for (int et = 0; et < 2; ++et)
                #pragma unroll
                for (int mt = 0; mt < 4; ++mt)
                    acc[et][mt] = __builtin_amdgcn_mfma_f32_16x16x32_bf16(
                        wfrag[s * 4 + mt], ef[et], acc[et][mt], 0, 0, 0);
        }
    }

    // ---- pipeline drain ----
    __syncthreads();                     // sync red writes of round R-1 (E1 of tile R-2)
    // E2 for tile R-2 (slot R&1 == (R-2)&1)
    if (R >= 2 && lane < 16) {
        int eo = wave * 16 + l15;
        long tt = t0 + (long)(R - 2) * G;
        out[tt * TILE_M + eo] = red[R & 1][0][eo] + red[R & 1][1][eo] + b2v;
    }
    // E1 for tile R-1
    {
        const int slot = (R - 1) & 1;
        #pragma unroll
        for (int et = 0; et < 2; ++et) {
            float v = 0.f;
            #pragma unroll
            for (int mt = 0; mt < 4; ++mt)
                #pragma unroll
                for (int rr = 0; rr < 4; ++rr) {
                    float h = acc[et][mt][rr] + b1v[mt][rr];
                    h = h > 0.f ? h : 0.f;
                    v += h * w2v[mt][rr];
                }
            v += __shfl_xor(v, 16);
            v += __shfl_xor(v, 32);
            if (lane < 16) red[slot][wh][we * 32 + et * 16 + l15] = v;
        }
    }
    __syncthreads();
    // E2 for tile R-1
    if (lane < 16) {
        int eo = wave * 16 + l15;
        long tt = t0 + (long)(R - 1) * G;
        out[tt * TILE_M + eo] = red[(R - 1) & 1][0][eo] + red[(R - 1) & 1][1][eo] + b2v;
    }
}

extern "C" void kernel_launch(void* const* d_in, const int* in_sizes, int n_in,
                              void* d_out, int out_size, void* d_ws, size_t ws_size,
                              hipStream_t stream) {
    const float* zd = (const float*)d_in[0];
    const float* zs = (const float*)d_in[1];
    const int*   row = (const int*)d_in[2];
    const int*   col = (const int*)d_in[3];
    const float* W1 = (const float*)d_in[4];
    const float* b1 = (const float*)d_in[5];
    const float* w2 = (const float*)d_in[6];
    const float* b2 = (const float*)d_in[7];
    float* out = (float*)d_out;

    const int nd = in_sizes[0];   // 10000*128
    const int ns = in_sizes[1];   // 15000*128
    const int E  = in_sizes[2];   // 1048576

    unsigned short* zd_b = (unsigned short*)d_ws;
    unsigned short* zs_b = zd_b + nd;

    const int total4 = (nd + ns) / 4;
    const int pgrid = (total4 + 255) / 256;
    hipLaunchKernelGGL(prep_tables, dim3(pgrid), dim3(256), 0, stream,
                       zd, zs, nd / 4, ns / 4, zd_b, zs_b);

    const int ntiles = E / TILE_M;   // 16384
    const int nblocks = 512;         // 2 blocks/CU (LDS-limited), R = 32 tiles/block
    hipLaunchKernelGGL(edge_mlp, dim3(nblocks), dim3(256), 0, stream,
                       zd_b, zs_b, row, col, W1, b1, w2, b2, out, ntiles);
}

// Round 7
// 164.064 us; speedup vs baseline: 1.0315x; 1.0315x over previous
//
#include <hip/hip_runtime.h>

typedef __attribute__((ext_vector_type(8))) short short8;
typedef __attribute__((ext_vector_type(4))) float floatx4;
typedef __attribute__((ext_vector_type(4))) float float4v;
typedef __attribute__((ext_vector_type(4))) unsigned short ushort4v;

#define TILE_M 64
#define TILE_SHORTS (TILE_M * 256)   // 16384 shorts = 32 KB single buffer
#define RTILES 4                     // contiguous tiles per block

static __device__ __forceinline__ unsigned short f2bf(float x) {
    unsigned int u = __builtin_bit_cast(unsigned int, x);
    unsigned int r = (u + 0x7FFFu + ((u >> 16) & 1u)) >> 16;
    return (unsigned short)r;
}

// async 16B global -> LDS (DMA, lands at lds_base + lane*16)
static __device__ __forceinline__ void gld16(const unsigned short* g, unsigned short* l) {
    __builtin_amdgcn_global_load_lds(
        (const __attribute__((address_space(1))) unsigned int*)g,
        (__attribute__((address_space(3))) unsigned int*)l, 16, 0, 0);
}

// One prep launch: tables fp32->bf16 (vectorized) + W1 [256k][128n] -> w1t [128n][256k] bf16
__global__ void prep_all(const float* __restrict__ zd, const float* __restrict__ zs,
                         const float* __restrict__ W1,
                         int nd4, int ns4,
                         unsigned short* __restrict__ outd, unsigned short* __restrict__ outs,
                         unsigned short* __restrict__ w1t) {
    int i = blockIdx.x * 256 + threadIdx.x;
    int total4 = nd4 + ns4;
    if (i < total4) {
        const float* src; unsigned short* dst; int j;
        if (i < nd4) { src = zd; dst = outd; j = i; }
        else         { src = zs; dst = outs; j = i - nd4; }
        float4v v = *reinterpret_cast<const float4v*>(src + (size_t)j * 4);
        ushort4v o;
        o.x = f2bf(v.x); o.y = f2bf(v.y); o.z = f2bf(v.z); o.w = f2bf(v.w);
        *reinterpret_cast<ushort4v*>(dst + (size_t)j * 4) = o;
    } else {
        int j = i - total4;
        if (j < 128 * 256) {
            int n = j >> 8;
            int k = j & 255;
            w1t[n * 256 + k] = f2bf(W1[k * 128 + n]);
        }
    }
}

// LDS tile layout (flat, DMA-compatible, XOR-swizzled):
// chunk slot c (16B) holds edge e = c>>5, physical chunk jx = c&31, storing
// logical k-chunk j = jx ^ (e&7) of edge e's 256-short concat row.
//
// Single-buffer pipeline per round r (tiles are contiguous: t = tile0 + r):
//   barrier A (drains DMA(t), syncs red(t-1)) -> out(t-1) -> K(t) ->
//   barrier B (buffer reads done) -> issue DMA(t+1) -> epilogue(t) -> red
// Cross-block overlap (3 blocks/CU) hides each block's barrier shadows.
__global__ __launch_bounds__(256, 3) void edge_mlp(
    const unsigned short* __restrict__ zd, const unsigned short* __restrict__ zs,
    const int* __restrict__ row, const int* __restrict__ col,
    const unsigned short* __restrict__ w1t,
    const float* __restrict__ b1, const float* __restrict__ w2,
    const float* __restrict__ b2, float* __restrict__ out)
{
    __shared__ unsigned short lds_a[TILE_SHORTS];   // 32 KB single buffer
    __shared__ float red[4][TILE_M];                // 1 KB

    const int tid  = threadIdx.x;
    const int lane = tid & 63;
    const int wave = tid >> 6;           // wave owns hidden [wave*32, wave*32+32)
    const int l15  = lane & 15;
    const int quad = lane >> 4;
    const int whbase = wave * 32;

    // ---- persistent W1 A-fragments for this wave's 32 hidden (64 VGPRs) ----
    // A[m=hidden][k]: m = whbase + mt*16 + l15, k = s*32 + quad*8 + j
    short8 wfrag[16];                    // [s*2 + mt]
    #pragma unroll
    for (int s = 0; s < 8; ++s)
        #pragma unroll
        for (int mt = 0; mt < 2; ++mt)
            wfrag[s * 2 + mt] = *reinterpret_cast<const short8*>(
                &w1t[(size_t)(whbase + mt * 16 + l15) * 256 + s * 32 + quad * 8]);

    // ---- persistent epilogue constants (16 VGPRs) ----
    float4v b1v[2], w2v[2];
    #pragma unroll
    for (int mt = 0; mt < 2; ++mt) {
        b1v[mt] = *reinterpret_cast<const float4v*>(&b1[whbase + mt * 16 + quad * 4]);
        w2v[mt] = *reinterpret_cast<const float4v*>(&w2[whbase + mt * 16 + quad * 4]);
    }
    const float b2v = b2[0];

    // ---- fixed staging geometry for this thread ----
    const int e0 = tid >> 5;             // edges e0 + 8i
    const int jxw = tid & 31;            // physical chunk this thread fills
    const int jlog = jxw ^ (e0 & 7);     // logical k-chunk it fetches
    const unsigned short* tab = (jlog >= 16) ? zs : zd;
    const int* idxp = (jlog >= 16) ? col : row;
    const int koff = (jlog & 15) * 8;

    // reader swizzle constants
    const int hb = (l15 >> 2) & 1;
    const int qx = quad ^ (l15 & 3);

    const long tile0 = (long)blockIdx.x * RTILES;

    // ---- prologue: idx(t0) -> DMA(t0) -> prefetch idx(t0+1) ----
    int nidx[8];
    #pragma unroll
    for (int i = 0; i < 8; ++i) nidx[i] = idxp[tile0 * TILE_M + e0 + 8 * i];
    #pragma unroll
    for (int i = 0; i < 8; ++i)
        gld16(tab + (size_t)nidx[i] * 128 + koff, &lds_a[2048 * i + 512 * wave]);
    #pragma unroll
    for (int i = 0; i < 8; ++i) nidx[i] = idxp[(tile0 + 1) * TILE_M + e0 + 8 * i];

    floatx4 acc[4][2];                   // [et][mt]

    for (int r = 0; r < RTILES; ++r) {
        const long t = tile0 + r;

        // barrier A: drains DMA(t) into lds_a; syncs red writes of round r-1
        __syncthreads();

        // out-write for tile t-1 (red synced by barrier A; red not rewritten
        // until after barrier B, so this read is race-free)
        if (r >= 1 && lane < 16) {
            int eo = wave * 16 + l15;
            out[(t - 1) * TILE_M + eo] =
                red[0][eo] + red[1][eo] + red[2][eo] + red[3][eo] + b2v;
        }

        // K-loop: C[hidden32, edge64] = W1quarter^T x Z
        #pragma unroll
        for (int et = 0; et < 4; ++et)
            #pragma unroll
            for (int mt = 0; mt < 2; ++mt)
                acc[et][mt] = (floatx4)(0.0f);

        #pragma unroll
        for (int s = 0; s < 8; ++s) {
            const int sx = s ^ hb;
            short8 ef[4];
            #pragma unroll
            for (int et = 0; et < 4; ++et) {
                int e = et * 16 + l15;
                ef[et] = *reinterpret_cast<const short8*>(&lds_a[e * 256 + sx * 32 + qx * 8]);
            }
            #pragma unroll
            for (int et = 0; et < 4; ++et)
                #pragma unroll
                for (int mt = 0; mt < 2; ++mt)
                    acc[et][mt] = __builtin_amdgcn_mfma_f32_16x16x32_bf16(
                        wfrag[s * 2 + mt], ef[et], acc[et][mt], 0, 0, 0);
        }

        // barrier B: all buffer reads for tile t complete
        __syncthreads();

        // issue DMA(t+1) immediately — flies during epilogue + other blocks' K-loops
        if (r + 1 < RTILES) {
            #pragma unroll
            for (int i = 0; i < 8; ++i)
                gld16(tab + (size_t)nidx[i] * 128 + koff, &lds_a[2048 * i + 512 * wave]);
            long t2 = t + 2; if (t2 >= tile0 + RTILES) t2 = tile0;
            #pragma unroll
            for (int i = 0; i < 8; ++i) nidx[i] = idxp[t2 * TILE_M + e0 + 8 * i];
        }

        // epilogue(t): reduce acc -> red (registers only; overlaps DMA flight)
        #pragma unroll
        for (int et = 0; et < 4; ++et) {
            float v = 0.f;
            #pragma unroll
            for (int mt = 0; mt < 2; ++mt)
                #pragma unroll
                for (int rr = 0; rr < 4; ++rr) {
                    float h = acc[et][mt][rr] + b1v[mt][rr];
                    h = h > 0.f ? h : 0.f;
                    v += h * w2v[mt][rr];
                }
            v += __shfl_xor(v, 16);
            v += __shfl_xor(v, 32);
            if (lane < 16) red[wave][et * 16 + l15] = v;
        }
    }

    // drain: out-write for the last tile
    __syncthreads();
    if (lane < 16) {
        int eo = wave * 16 + l15;
        out[(tile0 + RTILES - 1) * TILE_M + eo] =
            red[0][eo] + red[1][eo] + red[2][eo] + red[3][eo] + b2v;
    }
}

extern "C" void kernel_launch(void* const* d_in, const int* in_sizes, int n_in,
                              void* d_out, int out_size, void* d_ws, size_t ws_size,
                              hipStream_t stream) {
    const float* zd = (const float*)d_in[0];
    const float* zs = (const float*)d_in[1];
    const int*   row = (const int*)d_in[2];
    const int*   col = (const int*)d_in[3];
    const float* W1 = (const float*)d_in[4];
    const float* b1 = (const float*)d_in[5];
    const float* w2 = (const float*)d_in[6];
    const float* b2 = (const float*)d_in[7];
    float* out = (float*)d_out;

    const int nd = in_sizes[0];   // 10000*128
    const int ns = in_sizes[1];   // 15000*128
    const int E  = in_sizes[2];   // 1048576

    unsigned short* zd_b = (unsigned short*)d_ws;
    unsigned short* zs_b = zd_b + nd;
    unsigned short* w1t  = zs_b + ns;   // 128*256 bf16

    const int total_jobs = (nd + ns) / 4 + 128 * 256;
    const int pgrid = (total_jobs + 255) / 256;
    hipLaunchKernelGGL(prep_all, dim3(pgrid), dim3(256), 0, stream,
                       zd, zs, W1, nd / 4, ns / 4, zd_b, zs_b, w1t);

    const int ntiles = E / TILE_M;           // 16384
    const int nblocks = ntiles / RTILES;     // 4096 non-persistent blocks
    hipLaunchKernelGGL(edge_mlp, dim3(nblocks), dim3(256), 0, stream,
                       zd_b, zs_b, row, col, w1t, b1, w2, b2, out);
}

// Round 8
// 146.420 us; speedup vs baseline: 1.1558x; 1.1205x over previous
//
#include <hip/hip_runtime.h>

typedef __attribute__((ext_vector_type(8))) short short8;
typedef __attribute__((ext_vector_type(4))) float floatx4;
typedef __attribute__((ext_vector_type(4))) float float4v;
typedef __attribute__((ext_vector_type(4))) unsigned short ushort4v;

#define TILE_M 64
#define TILE_SHORTS (TILE_M * 256)   // 16384 shorts = 32 KB per buffer (flat, swizzled)

static __device__ __forceinline__ unsigned short f2bf(float x) {
    unsigned int u = __builtin_bit_cast(unsigned int, x);
    unsigned int r = (u + 0x7FFFu + ((u >> 16) & 1u)) >> 16;
    return (unsigned short)r;
}

// async 16B global -> LDS (DMA, lands at lds_base + lane*16)
static __device__ __forceinline__ void gld16(const unsigned short* g, unsigned short* l) {
    __builtin_amdgcn_global_load_lds(
        (const __attribute__((address_space(1))) unsigned int*)g,
        (__attribute__((address_space(3))) unsigned int*)l, 16, 0, 0);
}

// One prep launch: tables fp32->bf16 (vectorized) + W1 [256k][128n] -> w1t [128n][256k] bf16
__global__ void prep_all(const float* __restrict__ zd, const float* __restrict__ zs,
                         const float* __restrict__ W1,
                         int nd4, int ns4,
                         unsigned short* __restrict__ outd, unsigned short* __restrict__ outs,
                         unsigned short* __restrict__ w1t) {
    int i = blockIdx.x * 256 + threadIdx.x;
    int total4 = nd4 + ns4;
    if (i < total4) {
        const float* src; unsigned short* dst; int j;
        if (i < nd4) { src = zd; dst = outd; j = i; }
        else         { src = zs; dst = outs; j = i - nd4; }
        float4v v = *reinterpret_cast<const float4v*>(src + (size_t)j * 4);
        ushort4v o;
        o.x = f2bf(v.x); o.y = f2bf(v.y); o.z = f2bf(v.z); o.w = f2bf(v.w);
        *reinterpret_cast<ushort4v*>(dst + (size_t)j * 4) = o;
    } else {
        int j = i - total4;
        if (j < 128 * 256) {
            int n = j >> 8;
            int k = j & 255;
            w1t[n * 256 + k] = f2bf(W1[k * 128 + n]);
        }
    }
}

// LDS tile layout (flat, DMA-compatible, XOR-swizzled):
// chunk slot c (16B) holds edge e = c>>5, physical chunk jx = c&31, storing
// logical k-chunk j = jx ^ (e&7) of edge e's 256-short concat row.
//
// Software pipeline per round r (ONE barrier per round, nothing trapped before it
// except the K-loop itself):
//   barrier -> DMA(t_{r+1}) -> idx prefetch -> out(t_{r-2}) -> reduce(t_{r-1}) -> K(t_r)
__global__ __launch_bounds__(256, 2) void edge_mlp(
    const unsigned short* __restrict__ zd, const unsigned short* __restrict__ zs,
    const int* __restrict__ row, const int* __restrict__ col,
    const unsigned short* __restrict__ w1t,
    const float* __restrict__ b1, const float* __restrict__ w2,
    const float* __restrict__ b2, float* __restrict__ out, int ntiles)
{
    __shared__ unsigned short lds_a[2][TILE_SHORTS];  // 64 KB double buffer
    __shared__ float red[2][2][TILE_M];               // 1 KB, slot = tile_index & 1

    const int tid  = threadIdx.x;
    const int lane = tid & 63;
    const int wave = tid >> 6;
    const int wh   = wave >> 1;          // hidden half: [wh*64, wh*64+64)
    const int we   = wave & 1;           // edge half:   [we*32, we*32+32)
    const int l15  = lane & 15;
    const int quad = lane >> 4;
    const int whbase = wh * 64;

    // ---- persistent W1 A-fragments from prepped w1t (128 VGPRs, plain 16B loads) ----
    // A[m=hidden][k]: m = whbase + mt*16 + l15, k = s*32 + quad*8 + j
    short8 wfrag[32];                    // [s*4 + mt]
    #pragma unroll
    for (int s = 0; s < 8; ++s)
        #pragma unroll
        for (int mt = 0; mt < 4; ++mt)
            wfrag[s * 4 + mt] = *reinterpret_cast<const short8*>(
                &w1t[(size_t)(whbase + mt * 16 + l15) * 256 + s * 32 + quad * 8]);

    // ---- persistent epilogue constants (16 VGPRs) ----
    float4v b1v[4], w2v[4];
    #pragma unroll
    for (int mt = 0; mt < 4; ++mt) {
        b1v[mt] = *reinterpret_cast<const float4v*>(&b1[whbase + mt * 16 + quad * 4]);
        w2v[mt] = *reinterpret_cast<const float4v*>(&w2[whbase + mt * 16 + quad * 4]);
    }
    const float b2v = b2[0];

    // ---- fixed staging geometry for this thread ----
    const int e0 = tid >> 5;             // edges e0 + 8i
    const int jxw = tid & 31;            // physical chunk this thread fills
    const int jlog = jxw ^ (e0 & 7);     // logical k-chunk it fetches
    const unsigned short* tab = (jlog >= 16) ? zs : zd;
    const int* idxp = (jlog >= 16) ? col : row;
    const int koff = (jlog & 15) * 8;

    // reader swizzle constants
    const int hb = (l15 >> 2) & 1;
    const int qx = quad ^ (l15 & 3);

    const int G = gridDim.x;
    const int R = ntiles / G;            // 16384/512 = 32, uniform
    const long t0 = blockIdx.x;

    // ---- prologue: DMA tile t0 into buf 0; prefetch indices for t0+G ----
    int nidx[8];
    #pragma unroll
    for (int i = 0; i < 8; ++i) nidx[i] = idxp[t0 * TILE_M + e0 + 8 * i];
    #pragma unroll
    for (int i = 0; i < 8; ++i)
        gld16(tab + (size_t)nidx[i] * 128 + koff, &lds_a[0][2048 * i + 512 * wave]);
    {
        long t1 = (R >= 2) ? (t0 + G) : t0;
        #pragma unroll
        for (int i = 0; i < 8; ++i) nidx[i] = idxp[t1 * TILE_M + e0 + 8 * i];
    }

    floatx4 acc[2][4];                   // [et][mt]

    for (int r = 0; r < R; ++r) {
        const long t = t0 + (long)r * G;

        // single barrier: drains DMA(t) into buf[r&1]; syncs red writes of round r-1
        __syncthreads();

        // (a) issue async DMA for tile t+G into the other buffer — flies across
        // everything below plus the other block's work
        if (r + 1 < R) {
            #pragma unroll
            for (int i = 0; i < 8; ++i)
                gld16(tab + (size_t)nidx[i] * 128 + koff,
                      &lds_a[(r + 1) & 1][2048 * i + 512 * wave]);
        }
        // (b) prefetch indices for tile t+2G
        {
            long t2 = (r + 2 < R) ? (t0 + (long)(r + 2) * G) : t0;
            #pragma unroll
            for (int i = 0; i < 8; ++i) nidx[i] = idxp[t2 * TILE_M + e0 + 8 * i];
        }

        // (c) E2: out-write for tile t-2G (red slot r&1), spread over all 4 waves
        if (r >= 2 && lane < 16) {
            int eo = wave * 16 + l15;
            out[(t - 2 * G) * TILE_M + eo] =
                red[r & 1][0][eo] + red[r & 1][1][eo] + b2v;
        }

        // (d) E1: reduce acc of tile t-G into red slot (r-1)&1
        if (r >= 1) {
            const int slot = (r - 1) & 1;
            #pragma unroll
            for (int et = 0; et < 2; ++et) {
                float v = 0.f;
                #pragma unroll
                for (int mt = 0; mt < 4; ++mt)
                    #pragma unroll
                    for (int rr = 0; rr < 4; ++rr) {
                        float h = acc[et][mt][rr] + b1v[mt][rr];
                        h = h > 0.f ? h : 0.f;
                        v += h * w2v[mt][rr];
                    }
                v += __shfl_xor(v, 16);
                v += __shfl_xor(v, 32);
                if (lane < 16) red[slot][wh][we * 32 + et * 16 + l15] = v;
            }
        }

        // (e) K-loop: acc = W1half^T x Zhalf on buf[r&1]
        const unsigned short* buf = lds_a[r & 1];
        #pragma unroll
        for (int et = 0; et < 2; ++et)
            #pragma unroll
            for (int mt = 0; mt < 4; ++mt)
                acc[et][mt] = (floatx4)(0.0f);

        #pragma unroll
        for (int s = 0; s < 8; ++s) {
            const int sx = s ^ hb;
            short8 ef[2];
            #pragma unroll
            for (int et = 0; et < 2; ++et) {
                int e = we * 32 + et * 16 + l15;
                ef[et] = *reinterpret_cast<const short8*>(&buf[e * 256 + sx * 32 + qx * 8]);
            }
            #pragma unroll
            for (int et = 0; et < 2; ++et)
                #pragma unroll
                for (int mt = 0; mt < 4; ++mt)
                    acc[et][mt] = __builtin_amdgcn_mfma_f32_16x16x32_bf16(
                        wfrag[s * 4 + mt], ef[et], acc[et][mt], 0, 0, 0);
        }
    }

    // ---- pipeline drain ----
    __syncthreads();                     // syncs red writes of round R-1 (E1 of tile R-2)
    if (R >= 2 && lane < 16) {           // E2 for tile R-2 (slot R&1 == (R-2)&1)
        int eo = wave * 16 + l15;
        long tt = t0 + (long)(R - 2) * G;
        out[tt * TILE_M + eo] = red[R & 1][0][eo] + red[R & 1][1][eo] + b2v;
    }
    {                                    // E1 for tile R-1
        const int slot = (R - 1) & 1;
        #pragma unroll
        for (int et = 0; et < 2; ++et) {
            float v = 0.f;
            #pragma unroll
            for (int mt = 0; mt < 4; ++mt)
                #pragma unroll
                for (int rr = 0; rr < 4; ++rr) {
                    float h = acc[et][mt][rr] + b1v[mt][rr];
                    h = h > 0.f ? h : 0.f;
                    v += h * w2v[mt][rr];
                }
            v += __shfl_xor(v, 16);
            v += __shfl_xor(v, 32);
            if (lane < 16) red[slot][wh][we * 32 + et * 16 + l15] = v;
        }
    }
    __syncthreads();
    if (lane < 16) {                     // E2 for tile R-1
        int eo = wave * 16 + l15;
        long tt = t0 + (long)(R - 1) * G;
        out[tt * TILE_M + eo] = red[(R - 1) & 1][0][eo] + red[(R - 1) & 1][1][eo] + b2v;
    }
}

extern "C" void kernel_launch(void* const* d_in, const int* in_sizes, int n_in,
                              void* d_out, int out_size, void* d_ws, size_t ws_size,
                              hipStream_t stream) {
    const float* zd = (const float*)d_in[0];
    const float* zs = (const float*)d_in[1];
    const int*   row = (const int*)d_in[2];
    const int*   col = (const int*)d_in[3];
    const float* W1 = (const float*)d_in[4];
    const float* b1 = (const float*)d_in[5];
    const float* w2 = (const float*)d_in[6];
    const float* b2 = (const float*)d_in[7];
    float* out = (float*)d_out;

    const int nd = in_sizes[0];   // 10000*128
    const int ns = in_sizes[1];   // 15000*128
    const int E  = in_sizes[2];   // 1048576

    unsigned short* zd_b = (unsigned short*)d_ws;
    unsigned short* zs_b = zd_b + nd;
    unsigned short* w1t  = zs_b + ns;   // 128*256 bf16

    const int total_jobs = (nd + ns) / 4 + 128 * 256;
    const int pgrid = (total_jobs + 255) / 256;
    hipLaunchKernelGGL(prep_all, dim3(pgrid), dim3(256), 0, stream,
                       zd, zs, W1, nd / 4, ns / 4, zd_b, zs_b, w1t);

    const int ntiles = E / TILE_M;   // 16384
    const int nblocks = 512;         // 2 blocks/CU (LDS-limited), R = 32 rounds
    hipLaunchKernelGGL(edge_mlp, dim3(nblocks), dim3(256), 0, stream,
                       zd_b, zs_b, row, col, w1t, b1, w2, b2, out, ntiles);
}